// Round 1
// baseline (156.017 us; speedup 1.0000x reference)
//
#include <hip/hip_runtime.h>
#include <hip/hip_bf16.h>

// Problem constants (from reference): z [65536,256] f32, embeddings [1024,256] f32
// out = quantized_st [65536*256] f32 ++ loss scalar (out_size = 16777217)
#define NROWS 65536
#define DIM   256
#define KCB   1024
#define ND    (NROWS * DIM)

typedef float f32x4  __attribute__((ext_vector_type(4)));
typedef short bf16x8 __attribute__((ext_vector_type(8)));  // 8 bf16 in 4 VGPRs (guide §3)

// workspace layout (bytes)
#define WS_LOSS  0      // float
#define WS_ENORM 256    // float[1024]
#define WS_E     8192   // bf16 permuted [16 chunks][2048 ids][8] = 512 KiB
// total needed: 8192 + 524288 = 532480 B

// fp32 -> bf16 bits, round-to-nearest-even
static __device__ __forceinline__ short f2bf(float f) {
    union { float f; unsigned u; } v; v.f = f;
    unsigned u = v.u;
    unsigned r = (u + 0x7fffu + ((u >> 16) & 1u)) >> 16;
    return (short)(unsigned short)r;
}

// ---------------------------------------------------------------------------
// Prep: e_norm (fp32) + E converted to bf16 in MFMA-staging-permuted order.
// Permuted id within a 64-row chunk: id = (t*8+s)*64 + q*16 + l
//   where embedding row = t*16+l, d-chunk c = s*4+q (8 bf16 per chunk).
// This makes the main kernel's LDS staging a straight contiguous copy.
// ---------------------------------------------------------------------------
__global__ __launch_bounds__(256) void prep_e(const float* __restrict__ E,
                                              float* __restrict__ enorm,
                                              bf16x8* __restrict__ wsE,
                                              float* __restrict__ loss_acc) {
    __shared__ float part[64][4];
    const int tid = threadIdx.x;
    const int blk = blockIdx.x;  // 0..15, rows blk*64 ..

    if (blk == 0 && tid == 0) *loss_acc = 0.f;

    // phase 1: e_norm in fp32
    {
        const float4* E4 = (const float4*)E;
        int row = tid >> 2;      // 0..63
        int qq  = tid & 3;       // quarter of the row
        int base = (blk * 64 + row) * 64 + qq * 16;
        float s = 0.f;
#pragma unroll
        for (int u = 0; u < 16; ++u) {
            float4 f = E4[base + u];
            s += f.x * f.x + f.y * f.y + f.z * f.z + f.w * f.w;
        }
        part[row][qq] = s;
    }
    __syncthreads();
    if (tid < 64)
        enorm[blk * 64 + tid] = part[tid][0] + part[tid][1] + part[tid][2] + part[tid][3];

    // phase 2: permuted bf16 write (coalesced 16B stores)
    const float4* E4 = (const float4*)E;
#pragma unroll
    for (int j = 0; j < 8; ++j) {
        int id = tid + 256 * j;                 // 0..2047
        int l = id & 15, q = (id >> 4) & 3, s = (id >> 6) & 7, t = (id >> 9) & 3;
        int row = t * 16 + l;
        int c   = s * 4 + q;
        int fi  = (blk * 64 + row) * 64 + c * 2;
        float4 f0 = E4[fi], f1 = E4[fi + 1];
        bf16x8 o;
        o[0] = f2bf(f0.x); o[1] = f2bf(f0.y); o[2] = f2bf(f0.z); o[3] = f2bf(f0.w);
        o[4] = f2bf(f1.x); o[5] = f2bf(f1.y); o[6] = f2bf(f1.z); o[7] = f2bf(f1.w);
        wsE[blk * 2048 + id] = o;
    }
}

// ---------------------------------------------------------------------------
// Main: fused score-GEMM (bf16 MFMA) + argmin + gather + loss partial.
// Block = 256 thr (4 waves), 128 z-rows. Wave w owns rows w*32..w*32+31 as
// 2 row-tiles of 16; A-fragments live in registers for the whole K sweep.
// K-loop: 16 chunks of 64 embeddings staged in LDS (pre-permuted layout).
// ---------------------------------------------------------------------------
__global__ __launch_bounds__(256) void vq_main(const float* __restrict__ Z,
                                               const float* __restrict__ E,
                                               const float* __restrict__ enorm,
                                               const bf16x8* __restrict__ wsE,
                                               float* __restrict__ out,
                                               float* __restrict__ loss_acc) {
    __shared__ bf16x8 Es[2048];     // 32 KiB E chunk, staging order
    __shared__ float  enorm_s[64];
    __shared__ float  znorm_s[128];
    __shared__ int    closest_s[128];
    __shared__ float  blk_loss;

    const int tid  = threadIdx.x;
    const int w    = tid >> 6;
    const int lane = tid & 63;
    const int q    = lane >> 4;
    const int l    = lane & 15;
    const int blk  = blockIdx.x;

    if (tid == 0) blk_loss = 0.f;

    // ---- load A fragments (z rows) into registers; accumulate ||z||^2 fp32 ----
    bf16x8 zf[2][8];
    const float4* Z4 = (const float4*)Z;
#pragma unroll
    for (int rt = 0; rt < 2; ++rt) {
        int row = blk * 128 + w * 32 + rt * 16 + l;
        float zn = 0.f;
#pragma unroll
        for (int s = 0; s < 8; ++s) {
            int fi = row * 64 + s * 8 + q * 2;
            float4 f0 = Z4[fi], f1 = Z4[fi + 1];
            zn += f0.x * f0.x + f0.y * f0.y + f0.z * f0.z + f0.w * f0.w;
            zn += f1.x * f1.x + f1.y * f1.y + f1.z * f1.z + f1.w * f1.w;
            bf16x8 o;
            o[0] = f2bf(f0.x); o[1] = f2bf(f0.y); o[2] = f2bf(f0.z); o[3] = f2bf(f0.w);
            o[4] = f2bf(f1.x); o[5] = f2bf(f1.y); o[6] = f2bf(f1.z); o[7] = f2bf(f1.w);
            zf[rt][s] = o;
        }
        // each lane holds 64 of the row's 256 values; sum across the 4 q-lanes
        zn += __shfl_xor(zn, 16, 64);
        zn += __shfl_xor(zn, 32, 64);
        if (q == 0) znorm_s[w * 32 + rt * 16 + l] = zn;
    }

    float minv[2][4];
    int   mini[2][4];
#pragma unroll
    for (int rt = 0; rt < 2; ++rt)
#pragma unroll
        for (int r = 0; r < 4; ++r) { minv[rt][r] = 3.4e38f; mini[rt][r] = 0; }

    // ---- K sweep ----
    for (int kc = 0; kc < 16; ++kc) {
        __syncthreads();   // previous chunk's reads done (also covers znorm/blk_loss init)
        // stage: contiguous copy, coalesced global + stride-1 ds_write_b128
#pragma unroll
        for (int j = 0; j < 8; ++j) {
            int id = tid + 256 * j;
            Es[id] = wsE[kc * 2048 + id];
        }
        if (tid < 64) enorm_s[tid] = enorm[kc * 64 + tid];
        __syncthreads();

        f32x4 acc[2][4];
#pragma unroll
        for (int rt = 0; rt < 2; ++rt)
#pragma unroll
            for (int t = 0; t < 4; ++t) acc[rt][t] = (f32x4){0.f, 0.f, 0.f, 0.f};

#pragma unroll
        for (int s = 0; s < 8; ++s) {
            bf16x8 b0 = Es[(0 * 8 + s) * 64 + lane];
            bf16x8 b1 = Es[(1 * 8 + s) * 64 + lane];
            bf16x8 b2 = Es[(2 * 8 + s) * 64 + lane];
            bf16x8 b3 = Es[(3 * 8 + s) * 64 + lane];
            acc[0][0] = __builtin_amdgcn_mfma_f32_16x16x32_bf16(zf[0][s], b0, acc[0][0], 0, 0, 0);
            acc[0][1] = __builtin_amdgcn_mfma_f32_16x16x32_bf16(zf[0][s], b1, acc[0][1], 0, 0, 0);
            acc[0][2] = __builtin_amdgcn_mfma_f32_16x16x32_bf16(zf[0][s], b2, acc[0][2], 0, 0, 0);
            acc[0][3] = __builtin_amdgcn_mfma_f32_16x16x32_bf16(zf[0][s], b3, acc[0][3], 0, 0, 0);
            acc[1][0] = __builtin_amdgcn_mfma_f32_16x16x32_bf16(zf[1][s], b0, acc[1][0], 0, 0, 0);
            acc[1][1] = __builtin_amdgcn_mfma_f32_16x16x32_bf16(zf[1][s], b1, acc[1][1], 0, 0, 0);
            acc[1][2] = __builtin_amdgcn_mfma_f32_16x16x32_bf16(zf[1][s], b2, acc[1][2], 0, 0, 0);
            acc[1][3] = __builtin_amdgcn_mfma_f32_16x16x32_bf16(zf[1][s], b3, acc[1][3], 0, 0, 0);
        }

        // min update: C/D layout col = lane&15 (embedding), row = q*4+reg (z row)
#pragma unroll
        for (int t = 0; t < 4; ++t) {
            float en   = enorm_s[t * 16 + l];
            int   kidx = kc * 64 + t * 16 + l;
#pragma unroll
            for (int rt = 0; rt < 2; ++rt)
#pragma unroll
                for (int r = 0; r < 4; ++r) {
                    float sc = en - 2.f * acc[rt][t][r];
                    bool better = sc < minv[rt][r];   // strict '<': earliest k wins ties
                    mini[rt][r] = better ? kidx : mini[rt][r];
                    minv[rt][r] = better ? sc : minv[rt][r];
                }
        }
    }

    // ---- cross-lane argmin over the 16 column-lanes of each quad ----
    float lossp = 0.f;
#pragma unroll
    for (int rt = 0; rt < 2; ++rt)
#pragma unroll
        for (int r = 0; r < 4; ++r) {
            float v  = minv[rt][r];
            int   id = mini[rt][r];
#pragma unroll
            for (int m = 1; m <= 8; m <<= 1) {
                float ov = __shfl_xor(v, m, 64);
                int   oi = __shfl_xor(id, m, 64);
                if (ov < v || (ov == v && oi < id)) { v = ov; id = oi; }
            }
            if (l == 0) {
                int rloc = w * 32 + rt * 16 + q * 4 + r;
                closest_s[rloc] = id;
                lossp += v + znorm_s[rloc];   // ||z||^2 + ||e*||^2 - 2 z.e* = ||q - z||^2
            }
        }
    if (l == 0) atomicAdd(&blk_loss, lossp);
    __syncthreads();                      // closest_s + blk_loss visible
    if (tid == 0) atomicAdd(loss_acc, blk_loss);

    // ---- gather epilogue: out rows = E[closest] in fp32 (exact values) ----
    const float4* E4 = (const float4*)E;
    float4* O4 = (float4*)out;
#pragma unroll
    for (int u = 0; u < 32; ++u) {
        int idx = u * 256 + tid;          // 0..8191
        int row = idx >> 6;
        int c4  = idx & 63;
        int k   = closest_s[row];
        O4[(blk * 128 + row) * 64 + c4] = E4[k * 64 + c4];
    }
}

__global__ void finalize_loss(const float* __restrict__ loss_acc, float* __restrict__ out) {
    if (threadIdx.x == 0)
        out[ND] = 1.25f * (*loss_acc) / (float)ND;   // codebook + 0.25*commitment, both = mse
}

extern "C" void kernel_launch(void* const* d_in, const int* in_sizes, int n_in,
                              void* d_out, int out_size, void* d_ws, size_t ws_size,
                              hipStream_t stream) {
    const float* z = (const float*)d_in[0];
    const float* e = (const float*)d_in[1];
    float* out = (float*)d_out;
    char*  ws  = (char*)d_ws;
    float*  loss_acc = (float*)(ws + WS_LOSS);
    float*  enorm    = (float*)(ws + WS_ENORM);
    bf16x8* wsE      = (bf16x8*)(ws + WS_E);

    prep_e<<<16, 256, 0, stream>>>(e, enorm, wsE, loss_acc);
    vq_main<<<512, 256, 0, stream>>>(z, e, enorm, wsE, out, loss_acc);
    finalize_loss<<<1, 64, 0, stream>>>(loss_acc, out);
}